// Round 3
// baseline (211.017 us; speedup 1.0000x reference)
//
#include <hip/hip_runtime.h>

// Problem constants (setup_inputs: B=16, O=8192, K1=5, D=64, n_samples=2048)
#define K1 5
#define DIM 64
#define OCNT 8192
#define BLOCK 256
#define LPS 4                        // lanes per simplex
#define SPB (BLOCK / LPS)            // 64 simplices per block

__device__ __forceinline__ double det4(const double m[4][4]) {
    double c01 = m[2][0] * m[3][1] - m[2][1] * m[3][0];
    double c02 = m[2][0] * m[3][2] - m[2][2] * m[3][0];
    double c03 = m[2][0] * m[3][3] - m[2][3] * m[3][0];
    double c12 = m[2][1] * m[3][2] - m[2][2] * m[3][1];
    double c13 = m[2][1] * m[3][3] - m[2][3] * m[3][1];
    double c23 = m[2][2] * m[3][3] - m[2][3] * m[3][2];
    double d0 = m[1][1] * c23 - m[1][2] * c13 + m[1][3] * c12;
    double d1 = m[1][0] * c23 - m[1][2] * c03 + m[1][3] * c02;
    double d2 = m[1][0] * c13 - m[1][1] * c03 + m[1][3] * c01;
    double d3 = m[1][0] * c12 - m[1][1] * c02 + m[1][2] * c01;
    return m[0][0] * d0 - m[0][1] * d1 + m[0][2] * d2 - m[0][3] * d3;
}

__global__ __launch_bounds__(BLOCK) void cm_main_kernel(
        const float* __restrict__ pts,    // [B, O, K1, DIM] f32
        const int* __restrict__ sidx,     // [B, 2048] i32
        float* __restrict__ block_sums) { // [gridDim.x]
    const int g = threadIdx.x & (LPS - 1);     // lane-in-group: dims [16g..16g+15]
    const int s_local = threadIdx.x / LPS;     // simplex within block [0, 64)
    const int t = blockIdx.x * SPB + s_local;  // global simplex id
    const int b = t >> 11;                     // t / 2048
    const int o = sidx[t];                     // broadcast within group
    const float* base =
        pts + ((size_t)b * OCNT + (size_t)o) * (K1 * DIM) + g * 16;

    // ---- load: lane g holds dims [16g..16g+15] of all 5 rows (20 x b128) ----
    float4 x[K1][4];
#pragma unroll
    for (int i = 0; i < K1; ++i)
#pragma unroll
        for (int q = 0; q < 4; ++q)
            x[i][q] = *reinterpret_cast<const float4*>(base + i * DIM + q * 4);

    // ---- partial Gram: 15 unique entries (i<=j), 16-dim dot each ----
    float acc[15];
    {
        int k = 0;
#pragma unroll
        for (int i = 0; i < K1; ++i)
#pragma unroll
            for (int j = i; j < K1; ++j) {
                float s = 0.0f;
#pragma unroll
                for (int q = 0; q < 4; ++q) {
                    s = fmaf(x[i][q].x, x[j][q].x, s);
                    s = fmaf(x[i][q].y, x[j][q].y, s);
                    s = fmaf(x[i][q].z, x[j][q].z, s);
                    s = fmaf(x[i][q].w, x[j][q].w, s);
                }
                acc[k++] = s;
            }
    }
    // ---- reduce across the 4-lane group (2 butterfly rounds) ----
#pragma unroll
    for (int mask = 1; mask < LPS; mask <<= 1) {
#pragma unroll
        for (int k = 0; k < 15; ++k)
            acc[k] += __shfl_xor(acc[k], mask, 64);
    }

    // ---- stash Gram to LDS (stride 15: coprime with 32 banks) ----
    __shared__ float gram[SPB * 15];
    if (g == 0) {
#pragma unroll
        for (int k = 0; k < 15; ++k) gram[s_local * 15 + k] = acc[k];
    }
    __syncthreads();

    // ---- epilogue: wave 0 only, one thread per simplex ----
    if (threadIdx.x < SPB) {
        const float* gp = gram + threadIdx.x * 15;
        float G[K1][K1];
        {
            int k = 0;
#pragma unroll
            for (int i = 0; i < K1; ++i)
#pragma unroll
                for (int j = i; j < K1; ++j) {
                    float v = gp[k++];
                    G[i][j] = v;
                    G[j][i] = v;
                }
        }

        float S[K1];
        float T = 0.0f;
#pragma unroll
        for (int i = 0; i < K1; ++i) {
            S[i] = G[i][0] + G[i][1] + G[i][2] + G[i][3] + G[i][4];
            T += S[i];
        }
        float ci[K1];
#pragma unroll
        for (int i = 0; i < K1; ++i) ci[i] = S[i] * 0.2f;  // v_i . centroid
        const float cc = T * 0.04f;                        // ||centroid||^2

        // rose
        float nrm[K1];
#pragma unroll
        for (int i = 0; i < K1; ++i) {
            float r2 = G[i][i] - 2.0f * ci[i] + cc;
            r2 = fmaxf(r2, 0.0f);
            nrm[i] = fmaxf(sqrtf(r2), 1e-8f);
        }
        float sumcos = 0.0f;
#pragma unroll
        for (int i = 0; i < K1; ++i)
#pragma unroll
            for (int j = i + 1; j < K1; ++j) {
                float num = G[i][j] - ci[i] - ci[j] + cc;
                sumcos += num / (nrm[i] * nrm[j]);
            }
        const float rose = (sumcos * 0.1f + 1.0f) * 0.5f;  // cos_mean = sumcos/10

        // regularity
        float dmin = 3.4e38f, dmax = 0.0f;
#pragma unroll
        for (int i = 0; i < K1; ++i)
#pragma unroll
            for (int j = i + 1; j < K1; ++j) {
                float d2 = G[i][i] + G[j][j] - 2.0f * G[i][j];
                float dd = sqrtf(fmaxf(d2, 1e-12f));
                dmin = fminf(dmin, dd);
                dmax = fmaxf(dmax, dd);
            }
        const float reg = dmin / fmaxf(dmax, 1e-8f);

        // Cayley-Menger via edge-Gram det: vol = sqrt(det(W))/24
        double W[4][4];
#pragma unroll
        for (int a = 1; a < K1; ++a)
#pragma unroll
            for (int c = 1; c < K1; ++c)
                W[a - 1][c - 1] = (double)G[a][c] - (double)G[a][0] -
                                  (double)G[0][c] + (double)G[0][0];
        double dW = det4(W);
        double vol = sqrt(fmax(dW, 0.0)) * (1.0 / 24.0);
        const float degen = (vol < 1e-8) ? 1.0f : 0.0f;

        float loss = 0.5f * (1.0f - rose) + 0.3f * (1.0f - reg) + 0.2f * degen;

        // wave-0 reduction (all 64 lanes active here)
#pragma unroll
        for (int off = 32; off > 0; off >>= 1)
            loss += __shfl_down(loss, off, 64);
        if (threadIdx.x == 0) block_sums[blockIdx.x] = loss;
    }
}

__global__ __launch_bounds__(BLOCK) void cm_final_kernel(
        const float* __restrict__ block_sums, float* __restrict__ out,
        int nblocks, float inv_n) {
    float v = 0.0f;
    for (int i = threadIdx.x; i < nblocks; i += BLOCK) v += block_sums[i];
#pragma unroll
    for (int off = 32; off > 0; off >>= 1)
        v += __shfl_down(v, off, 64);
    __shared__ float wsum[BLOCK / 64];
    const int lane = threadIdx.x & 63;
    const int wave = threadIdx.x >> 6;
    if (lane == 0) wsum[wave] = v;
    __syncthreads();
    if (threadIdx.x == 0) {
        float s = 0.0f;
#pragma unroll
        for (int w = 0; w < BLOCK / 64; ++w) s += wsum[w];
        out[0] = s * inv_n;
    }
}

extern "C" void kernel_launch(void* const* d_in, const int* in_sizes, int n_in,
                              void* d_out, int out_size, void* d_ws, size_t ws_size,
                              hipStream_t stream) {
    const float* pts = (const float*)d_in[0];   // [16, 8192, 5, 64] f32
    const int* sidx  = (const int*)d_in[1];     // [16, 2048] i32
    float* out = (float*)d_out;                 // scalar f32
    float* block_sums = (float*)d_ws;

    const int nsimp = in_sizes[1];              // 32768
    const int nblocks = nsimp / SPB;            // 512

    cm_main_kernel<<<nblocks, BLOCK, 0, stream>>>(pts, sidx, block_sums);
    cm_final_kernel<<<1, BLOCK, 0, stream>>>(block_sums, out, nblocks,
                                             1.0f / (float)nsimp);
}